// Round 7
// baseline (293.158 us; speedup 1.0000x reference)
//
#include <hip/hip_runtime.h>
#include <hip/hip_bf16.h>
#include <math.h>

#define NNODES 8192
#define NEDGES 131072
#define HID    512
#define UU     16
#define MM     512
#define NQKVS  2048   // packed q|k|v|s columns

#if __has_builtin(__builtin_amdgcn_cvt_pk_f32_fp8) && __has_builtin(__builtin_amdgcn_cvt_pk_fp8_f32)
#define HAVE_FP8 1
#else
#define HAVE_FP8 0
#endif

#define KSCALE 16.0f
#define KISCALE (0.125f / 16.0f)   // score = (q . 16k) * 0.125/16

typedef __attribute__((ext_vector_type(8))) short bf16x8;
typedef __attribute__((ext_vector_type(4))) float f32x4;
typedef __attribute__((ext_vector_type(2))) float f32x2;

__device__ __forceinline__ float bf2f(ushort u) {
    return __uint_as_float(((unsigned)u) << 16);
}
__device__ __forceinline__ ushort f2bf(float f) {
    unsigned x = __float_as_uint(f);
    return (ushort)((x + 0x7fffu + ((x >> 16) & 1u)) >> 16);
}

// ---------------- weight transpose+convert + bias pack (fused) ----------------
__global__ __launch_bounds__(256) void k_wtb(
    const float* __restrict__ Wq, const float* __restrict__ Wk,
    const float* __restrict__ Wv, const float* __restrict__ Ws,
    const float* __restrict__ bq, const float* __restrict__ bk,
    const float* __restrict__ bv, const float* __restrict__ bs,
    ushort* __restrict__ Wt, float* __restrict__ bcat)
{
    __shared__ float tile[64][65];
    int z = blockIdx.z;
    int t = threadIdx.x;
    if (z == 12) {   // bias pack: 24 of the 64 (x,y) blocks
        int id = blockIdx.y * 8 + blockIdx.x;
        if (id < 24) {
            int i = id * 256 + t;                 // [3][2048]
            int l = i >> 11, j = i & 2047;
            int which = j >> 9, jj = j & 511;
            const float* b = which == 0 ? bq : which == 1 ? bk : which == 2 ? bv : bs;
            bcat[i] = b[l * HID + jj];
        }
        return;
    }
    int l = z >> 2, which = z & 3;
    const float* src = (which == 0 ? Wq : which == 1 ? Wk : which == 2 ? Wv : Ws)
                       + (size_t)l * HID * HID;
    int k0 = blockIdx.x * 64, c0 = blockIdx.y * 64;
#pragma unroll
    for (int i = 0; i < 16; ++i) {
        int idx = i * 256 + t;
        int r = idx >> 6, c = idx & 63;
        tile[r][c] = src[(size_t)(k0 + r) * HID + c0 + c];
    }
    __syncthreads();
    ushort* dst = Wt + ((size_t)l * NQKVS + which * HID + c0) * HID + k0;
#pragma unroll
    for (int i = 0; i < 16; ++i) {
        int idx = i * 256 + t;
        int r = idx >> 6, c = idx & 63;
        dst[(size_t)r * HID + c] = f2bf(tile[c][r]);
    }
}

// ---------------- layer-0 linear (in=6) with fused feature build ----------------
__global__ __launch_bounds__(256) void k_lin0(
    const float* __restrict__ mc, const float* __restrict__ speeds,
    const float* __restrict__ dist, const float* __restrict__ ttg,
    const int* __restrict__ mask,
    const float* __restrict__ Wq0, const float* __restrict__ bq0,
    const float* __restrict__ Wk0, const float* __restrict__ bk0,
    const float* __restrict__ Wv0, const float* __restrict__ bv0,
    const float* __restrict__ Ws0, const float* __restrict__ bs0,
    ushort* __restrict__ Y, unsigned char* __restrict__ Kf8)
{
    int n = blockIdx.x;                // node
    int u = n >> 9, m = n & 511;
    float x[6];
    x[0] = mc[m * 2 + 0];
    x[1] = mc[m * 2 + 1];
    x[2] = (float)mask[u * MM + m];
    x[3] = speeds[u];
    x[4] = dist[u * MM + m];
    x[5] = ttg[u * MM + m];

    int j = threadIdx.x;               // 0..255 -> cols j*8..j*8+7
    int col0 = j * 8;
    int which = col0 >> 9, jj = col0 & 511;
    const float* W = which == 0 ? Wq0 : which == 1 ? Wk0 : which == 2 ? Wv0 : Ws0;
    const float* b = which == 0 ? bq0 : which == 1 ? bk0 : which == 2 ? bv0 : bs0;
    float s[8];
#pragma unroll
    for (int uu = 0; uu < 8; ++uu) s[uu] = b[jj + uu];
#pragma unroll
    for (int t = 0; t < 6; ++t)
#pragma unroll
        for (int uu = 0; uu < 8; ++uu)
            s[uu] = fmaf(x[t], W[t * HID + jj + uu], s[uu]);
    bf16x8 o8;
#pragma unroll
    for (int uu = 0; uu < 8; ++uu) o8[uu] = (short)f2bf(s[uu]);
    *(bf16x8*)(Y + (size_t)n * NQKVS + col0) = o8;
#if HAVE_FP8
    if (which == 1) {   // k quarter -> fp8 copy (scaled)
        int w0 = __builtin_amdgcn_cvt_pk_fp8_f32(s[0] * KSCALE, s[1] * KSCALE, 0, false);
        w0     = __builtin_amdgcn_cvt_pk_fp8_f32(s[2] * KSCALE, s[3] * KSCALE, w0, true);
        int w1 = __builtin_amdgcn_cvt_pk_fp8_f32(s[4] * KSCALE, s[5] * KSCALE, 0, false);
        w1     = __builtin_amdgcn_cvt_pk_fp8_f32(s[6] * KSCALE, s[7] * KSCALE, w1, true);
        uint2 uu2; uu2.x = (unsigned)w0; uu2.y = (unsigned)w1;
        *(uint2*)(Kf8 + (size_t)n * HID + jj) = uu2;
    }
#endif
}

// ---------------- bf16 MFMA GEMM: Y[8192][2048] = X[8192][512] @ Wt^T + bias ----------------
// 128x128 tile, BK=32, 4 waves (2x2), 32 KB LDS double-buffered -> 4 blocks/CU
// (launch_bounds(256,4) caps VGPR at 128 -> 16 waves/CU overlap).
// LDS: per K-tile 128 rows x 128B; each row = A 64B + B 64B, halves SWAPPED on
// (row&4) and 16B slots XOR'd by (row&3) -> a/b ds_read_b128 spans all 32 banks
// across 8 rows (2-way only = free). Stage writes are linear 16B/lane; the
// inverse permutation is applied on the per-lane GLOBAL source address (rule #21).
// Counted vmcnt(4): 2 K-tiles in flight, never drained until the last tile.
#define GBM 128
#define GBN 128
#define GBK 32
#define BUF32 16384             // 128 rows x 128 B (A+B interleaved)

#define VMCNT(n) asm volatile("s_waitcnt vmcnt(" #n ")" ::: "memory")

__device__ __forceinline__ void stage32(
    const ushort* __restrict__ Ag, const ushort* __restrict__ Bg,
    char* __restrict__ buf, int t)
{
#pragma unroll
    for (int i = 0; i < 4; ++i) {
        int slot = i * 256 + t;          // 0..1023 (16B slots)
        int row  = slot >> 3;            // 0..127
        int sl8  = slot & 7;             // slot within 128B row
        int h    = sl8 >> 2;             // which 64B half
        int kqs  = sl8 & 3;
        int hA   = (row >> 2) & 1;       // half holding A for this row
        int kq   = kqs ^ (row & 3);      // inverse slot swizzle
        const ushort* src = (h == hA ? Ag : Bg) + (size_t)row * HID + kq * 8;
        __builtin_amdgcn_global_load_lds(
            (const __attribute__((address_space(1))) void*)src,
            (__attribute__((address_space(3))) void*)(buf + slot * 16), 16, 0, 0);
    }
}

__global__ __launch_bounds__(256, 4) void k_gemm(
    const ushort* __restrict__ A,    // [8192][512] bf16
    const ushort* __restrict__ Bt,   // [2048][512] bf16 (weights, [n][k])
    const float* __restrict__ bias,  // [2048] fp32
    ushort* __restrict__ Y,          // [8192][2048] bf16
    unsigned char* __restrict__ Kf8) // [8192][512] fp8 (k quarter, scaled)
{
    __shared__ char lds[2 * BUF32];  // 32768 B
    const int t = threadIdx.x;
    // bijective XCD remap: 1024 blocks -> 8 XCDs x (8 m-tiles x 16 n-tiles)
    const int bid = blockIdx.x;
    const int xcd = bid & 7;
    const int ii  = bid >> 3;                 // 0..127
    const int mi  = (xcd << 3) | (ii & 7);    // 0..63
    const int ni  = ii >> 3;                  // 0..15
    const int m0 = mi * GBM, n0 = ni * GBN;

    const int wid = t >> 6, lane = t & 63;
    const int wr = wid >> 1, wc = wid & 1;    // 2x2 waves, 64x64 out each
    const int l15 = lane & 15, lkq = lane >> 4;   // lkq = K-chunk 0..3

    f32x4 acc[4][4] = {};

    const ushort* Ab = A + (size_t)m0 * HID;
    const ushort* Bb = Bt + (size_t)n0 * HID;

    stage32(Ab, Bb, lds, t);                       // T0 -> buf0
    stage32(Ab + GBK, Bb + GBK, lds + BUF32, t);   // T1 -> buf1

    const int NKT = HID / GBK;   // 16
#pragma unroll
    for (int T = 0; T < NKT; ++T) {
        if (T < NKT - 1) { VMCNT(4); } else { VMCNT(0); }   // tile T's loads done
        __builtin_amdgcn_s_barrier();
        __builtin_amdgcn_sched_barrier(0);
        const char* lb_ = lds + (T & 1) * BUF32;
        bf16x8 a[4], b[4];
#pragma unroll
        for (int i = 0; i < 4; ++i) {
            int row = wr * 64 + i * 16 + l15;
            a[i] = *(const bf16x8*)(lb_ + row * 128 + ((row & 4) << 4)
                                    + ((lkq ^ (row & 3)) << 4));
        }
#pragma unroll
        for (int j = 0; j < 4; ++j) {
            int row = wc * 64 + j * 16 + l15;
            b[j] = *(const bf16x8*)(lb_ + row * 128 + (((row & 4) ^ 4) << 4)
                                    + ((lkq ^ (row & 3)) << 4));
        }
        __builtin_amdgcn_s_setprio(1);
#pragma unroll
        for (int i = 0; i < 4; ++i)
#pragma unroll
            for (int j = 0; j < 4; ++j)
                acc[i][j] = __builtin_amdgcn_mfma_f32_16x16x32_bf16(a[i], b[j], acc[i][j], 0, 0, 0);
        __builtin_amdgcn_s_setprio(0);
        __builtin_amdgcn_s_barrier();              // all waves done reading buf[T&1]
        __builtin_amdgcn_sched_barrier(0);
        if (T + 2 < NKT)
            stage32(Ab + (T + 2) * GBK, Bb + (T + 2) * GBK,
                    lds + (T & 1) * BUF32, t);
    }

    const bool kquad = ((n0 >> 9) == 1);   // cols [512,1024) = k quarter
    // epilogue: C/D layout col=lane&15, row=(lane>>4)*4+reg
#pragma unroll
    for (int i = 0; i < 4; ++i) {
        int row = m0 + wr * 64 + i * 16 + lkq * 4;
#pragma unroll
        for (int j = 0; j < 4; ++j) {
            int col = n0 + wc * 64 + j * 16 + l15;
            float bc = bias[col];
            f32x4 r = acc[i][j];
#pragma unroll
            for (int g = 0; g < 4; ++g) {
                float val = r[g] + bc;
                Y[(size_t)(row + g) * NQKVS + col] = f2bf(val);
#if HAVE_FP8
                if (kquad) {
                    int pk = __builtin_amdgcn_cvt_pk_fp8_f32(val * KSCALE, val * KSCALE, 0, false);
                    Kf8[(size_t)(row + g) * HID + (col - 512)] = (unsigned char)(pk & 0xff);
                }
#endif
            }
        }
    }
}

// ---------------- CSR build ----------------
__global__ __launch_bounds__(256) void k_hist(const int* __restrict__ dst, int* __restrict__ cnt)
{
    int e = blockIdx.x * blockDim.x + threadIdx.x;
    if (e < NEDGES) atomicAdd(&cnt[dst[e]], 1);
}

// parallel scan: 1024 threads, 8 elems each, wave-scan + cross-wave offsets
__global__ __launch_bounds__(1024) void k_scan(const int* __restrict__ cnt, int* __restrict__ indptr)
{
    __shared__ int wsum[16];
    __shared__ int woff[16];
    int t = threadIdx.x;
    int base = t * 8;
    int v[8];
    int s = 0;
#pragma unroll
    for (int i = 0; i < 8; ++i) { v[i] = cnt[base + i]; s += v[i]; }
    int lane = t & 63, w = t >> 6;
    int incl = s;
#pragma unroll
    for (int off = 1; off < 64; off <<= 1) {
        int u = __shfl_up(incl, off);
        if (lane >= off) incl += u;
    }
    if (lane == 63) wsum[w] = incl;
    __syncthreads();
    if (t == 0) {
        int run = 0;
#pragma unroll
        for (int i = 0; i < 16; ++i) { woff[i] = run; run += wsum[i]; }
    }
    __syncthreads();
    int run = woff[w] + incl - s;     // exclusive prefix for this chunk
#pragma unroll
    for (int i = 0; i < 8; ++i) { indptr[base + i] = run; run += v[i]; }
    if (t == 1023) indptr[NNODES] = run;
}

__global__ __launch_bounds__(256) void k_scatter(
    const int* __restrict__ src, const int* __restrict__ dst,
    const int* __restrict__ indptr, int* __restrict__ cursor, int* __restrict__ ssrc)
{
    int e = blockIdx.x * blockDim.x + threadIdx.x;
    if (e >= NEDGES) return;
    int d = dst[e];
    int p = atomicAdd(&cursor[d], 1);
    ssrc[indptr[d] + p] = src[e];
}

// ---------------- per-node attention (1 wave/node, 4 nodes/block), 4-deep prefetch ----------------
// lane l handles channels [l*8, l*8+8); heads are 8-lane groups (shfl_xor 1,2,4).
// k gathered from fp8 (scaled x16), v from bf16 Y.
__global__ __launch_bounds__(256) void k_attn(
    const int* __restrict__ indptr, const int* __restrict__ ssrc,
    const ushort* __restrict__ Y,   // [N][2048] packed q|k|v|s
    const unsigned char* __restrict__ Kf8,  // [N][512] fp8
    ushort* __restrict__ X)         // [N][512] bf16 out
{
    int n = blockIdx.x * 4 + (threadIdx.x >> 6);
    if (n >= NNODES) return;
    int l = threadIdx.x & 63;
    int cbase = l * 8;
    const ushort* yq = Y + (size_t)n * NQKVS + cbase;
    float qf[8];
    {
        bf16x8 q8 = *(const bf16x8*)yq;
#pragma unroll
        for (int j = 0; j < 8; ++j) qf[j] = bf2f((ushort)q8[j]);
    }
    float mrun = -INFINITY, ssum = 0.f;
    float acc[8] = {};
    int e0 = indptr[n], e1 = indptr[n + 1];

#if HAVE_FP8
    uint2 kA = {}, kB = {}, kC = {}, kD = {};
#define KLOAD(K_, s_) K_ = *(const uint2*)(Kf8 + (size_t)(s_) * HID + cbase)
#else
    bf16x8 kA = {}, kB = {}, kC = {}, kD = {};
#define KLOAD(K_, s_) K_ = *(const bf16x8*)(Y + (size_t)(s_) * NQKVS + 512 + cbase)
#endif
    bf16x8 vA = {}, vB = {}, vC = {}, vD = {};

#define LOADKV(K_, V_, idx) \
    if ((idx) < e1) { int s_ = ssrc[idx]; KLOAD(K_, s_); \
        V_ = *(const bf16x8*)(Y + (size_t)s_ * NQKVS + 1024 + cbase); }

#if HAVE_FP8
#define DOTK(K_, part) { \
        f32x2 k01 = __builtin_amdgcn_cvt_pk_f32_fp8((int)K_.x, false); \
        f32x2 k23 = __builtin_amdgcn_cvt_pk_f32_fp8((int)K_.x, true); \
        f32x2 k45 = __builtin_amdgcn_cvt_pk_f32_fp8((int)K_.y, false); \
        f32x2 k67 = __builtin_amdgcn_cvt_pk_f32_fp8((int)K_.y, true); \
        part = fmaf(qf[0], k01.x, part); part = fmaf(qf[1], k01.y, part); \
        part = fmaf(qf[2], k23.x, part); part = fmaf(qf[3], k23.y, part); \
        part = fmaf(qf[4], k45.x, part); part = fmaf(qf[5], k45.y, part); \
        part = fmaf(qf[6], k67.x, part); part = fmaf(qf[7], k67.y, part); }
#define SCOREMUL KISCALE
#else
#define DOTK(K_, part) { _Pragma("unroll") \
        for (int j = 0; j < 8; ++j) part = fmaf(qf[j], bf2f((ushort)K_[j]), part); }
#define SCOREMUL 0.125f
#endif

#define PROC(K_, V_) { \
        float part = 0.f; \
        DOTK(K_, part); \
        part += __shfl_xor(part, 1); \
        part += __shfl_xor(part, 2); \
        part += __shfl_xor(part, 4); \
        float score = part * SCOREMUL; \
        float mnew = fmaxf(mrun, score); \
        float sc = __expf(mrun - mnew); \
        float p = __expf(score - mnew); \
        ssum = ssum * sc + p; \
        _Pragma("unroll") \
        for (int j = 0; j < 8; ++j) acc[j] = fmaf(acc[j], sc, p * bf2f((ushort)V_[j])); \
        mrun = mnew; }

    LOADKV(kA, vA, e0 + 0);
    LOADKV(kB, vB, e0 + 1);
    LOADKV(kC, vC, e0 + 2);
    LOADKV(kD, vD, e0 + 3);
    for (int e = e0; e < e1; e += 4) {
        PROC(kA, vA); LOADKV(kA, vA, e + 4);
        if (e + 1 < e1) { PROC(kB, vB); LOADKV(kB, vB, e + 5); }
        if (e + 2 < e1) { PROC(kC, vC); LOADKV(kC, vC, e + 6); }
        if (e + 3 < e1) { PROC(kD, vD); LOADKV(kD, vD, e + 7); }
    }
    float inv = ssum > 0.f ? 1.f / ssum : 0.f;
    bf16x8 o8;
#pragma unroll
    for (int j = 0; j < 8; ++j) {
        float o = fmaxf(fmaf(acc[j], inv, bf2f(yq[1536 + j])), 0.f);  // + skip, ReLU
        o8[j] = (short)f2bf(o);
    }
    *(bf16x8*)(X + (size_t)n * HID + cbase) = o8;
}

// ---------------- pooling: xsumP[u][p][c] = partial sums over 64 rows ----------------
__global__ __launch_bounds__(512) void k_pool(const ushort* __restrict__ X, float* __restrict__ xsumP)
{
    int u = blockIdx.x;
    int pp = blockIdx.y;               // 0..7
    int c = threadIdx.x;
    const ushort* base = X + ((size_t)u * MM + pp * 64) * HID + c;
    float s = 0.f;
    for (int m = 0; m < 64; ++m) s += bf2f(base[(size_t)m * HID]);
    xsumP[((size_t)u * 8 + pp) * HID + c] = s;
}

// ---------------- fused: emb = xsum @ Wout + M*bout, then actor/critic head ----------------
__global__ __launch_bounds__(512) void k_embhead(
    const float* __restrict__ xsumP, const float* __restrict__ Wout,
    const float* __restrict__ bout,
    const float* __restrict__ uavs, const float* __restrict__ speeds,
    const float* __restrict__ Wc1, const float* __restrict__ bc1,
    const float* __restrict__ Wc2, const float* __restrict__ bc2,
    float* __restrict__ out)
{
    __shared__ float xs[HID];
    __shared__ float comb[67];
    __shared__ float red[128];
    int u = blockIdx.x, c = threadIdx.x;
    float s = 0.f;
#pragma unroll
    for (int p = 0; p < 8; ++p) s += xsumP[((size_t)u * 8 + p) * HID + c];
    xs[c] = s;
    __syncthreads();
    if (c < 64) {
        float a = 0.f;
        for (int i = 0; i < HID; ++i) a = fmaf(xs[i], Wout[i * 64 + c], a);
        comb[2 + c] = a + 512.0f * bout[c];
    }
    if (c == 64) { comb[0] = uavs[u * 2]; comb[1] = uavs[u * 2 + 1]; }
    if (c == 65) comb[66] = speeds[u];
    __syncthreads();
    if (c < 128) {
        float a = bc1[c];
        for (int i = 0; i < 67; ++i) a = fmaf(comb[i], Wc1[i * 128 + c], a);
        a = fmaxf(a, 0.f);
        red[c] = a * Wc2[c];
    }
    __syncthreads();
    for (int sft = 64; sft > 0; sft >>= 1) {
        if (c < sft) red[c] += red[c + sft];
        __syncthreads();
    }
    if (c == 0) {
        out[u]      = 1.0f;                 // softmax over singleton axis
        out[16 + u] = red[0] + bc2[0];
    }
}

extern "C" void kernel_launch(void* const* d_in, const int* in_sizes, int n_in,
                              void* d_out, int out_size, void* d_ws, size_t ws_size,
                              hipStream_t stream)
{
    const float* mission_coords = (const float*)d_in[0];
    const float* uavs_info      = (const float*)d_in[1];
    const float* speeds         = (const float*)d_in[2];
    const float* dist_matrix    = (const float*)d_in[3];
    const float* timetogo       = (const float*)d_in[4];
    const int*   action_mask    = (const int*)d_in[5];
    const int*   edge_index     = (const int*)d_in[6];
    const float* Wq0 = (const float*)d_in[8];  const float* bq0 = (const float*)d_in[9];
    const float* Wk0 = (const float*)d_in[10]; const float* bk0 = (const float*)d_in[11];
    const float* Wv0 = (const float*)d_in[12]; const float* bv0 = (const float*)d_in[13];
    const float* Ws0 = (const float*)d_in[14]; const float* bs0 = (const float*)d_in[15];
    const float* Wq  = (const float*)d_in[16]; const float* bq  = (const float*)d_in[17];
    const float* Wk  = (const float*)d_in[18]; const float* bk  = (const float*)d_in[19];
    const float* Wv  = (const float*)d_in[20]; const float* bv  = (const float*)d_in[21];
    const float* Ws  = (const float*)d_in[22]; const float* bs  = (const float*)d_in[23];
    const float* Wout = (const float*)d_in[24]; const float* bout = (const float*)d_in[25];
    const float* Wc1 = (const float*)d_in[30]; const float* bc1 = (const float*)d_in[31];
    const float* Wc2 = (const float*)d_in[32]; const float* bc2 = (const float*)d_in[33];
    float* out = (float*)d_out;

    const int* e_src = edge_index;
    const int* e_dst = edge_index + NEDGES;

    // ---- workspace carve ----
    char* p = (char*)d_ws;
    ushort* Ybf = (ushort*)p;  p += (size_t)NNODES * NQKVS * 2;   // 32 MB
    ushort* Xbf = (ushort*)p;  p += (size_t)NNODES * HID * 2;     // 8 MB
    ushort* Wt  = (ushort*)p;  p += (size_t)3 * NQKVS * HID * 2;  // 6 MB
    unsigned char* Kf8 = (unsigned char*)p; p += (size_t)NNODES * HID; // 4 MB
    float* bcat = (float*)p;   p += (size_t)3 * NQKVS * 4;
    float* xsumP = (float*)p;  p += (size_t)UU * 8 * HID * 4;
    int* cnt    = (int*)p;     p += (size_t)NNODES * 4;           // cnt+cursor adjacent
    int* cursor = (int*)p;     p += (size_t)NNODES * 4;
    int* indptr = (int*)p;     p += (size_t)(NNODES + 1) * 4;
    int* ssrc   = (int*)p;     p += (size_t)NEDGES * 4;

    hipMemsetAsync(cnt, 0, 2 * NNODES * sizeof(int), stream);     // cnt + cursor

    // ---- prep: weights+bias (fused), CSR ----
    k_wtb<<<dim3(8, 8, 13), 256, 0, stream>>>(Wq, Wk, Wv, Ws, bq, bk, bv, bs, Wt, bcat);
    k_hist<<<NEDGES / 256, 256, 0, stream>>>(e_dst, cnt);
    k_scan<<<1, 1024, 0, stream>>>(cnt, indptr);
    k_scatter<<<NEDGES / 256, 256, 0, stream>>>(e_src, e_dst, indptr, cursor, ssrc);

    // ---- layer 0 (in=6, fused feature build) ----
    k_lin0<<<NNODES, 256, 0, stream>>>(mission_coords, speeds, dist_matrix, timetogo,
                                       action_mask, Wq0, bq0, Wk0, bk0, Wv0, bv0,
                                       Ws0, bs0, Ybf, Kf8);
    k_attn<<<NNODES / 4, 256, 0, stream>>>(indptr, ssrc, Ybf, Kf8, Xbf);

    // ---- layers 1..3: fused q|k|v|s MFMA GEMM (128^2 BK32, 4 blk/CU) + attention ----
    const int ngblocks = (NNODES / GBM) * (NQKVS / GBN);   // 64*16 = 1024
    for (int l = 0; l < 3; ++l) {
        k_gemm<<<ngblocks, 256, 0, stream>>>(Xbf, Wt + (size_t)l * NQKVS * HID,
                                             bcat + l * NQKVS, Ybf, Kf8);
        k_attn<<<NNODES / 4, 256, 0, stream>>>(indptr, ssrc, Ybf, Kf8, Xbf);
    }

    // ---- pooling + fused embedding/head ----
    k_pool<<<dim3(UU, 8), 512, 0, stream>>>(Xbf, xsumP);
    k_embhead<<<UU, 512, 0, stream>>>(xsumP, Wout, bout, uavs_info, speeds,
                                      Wc1, bc1, Wc2, bc2, out);
}

// Round 8
// 269.434 us; speedup vs baseline: 1.0880x; 1.0880x over previous
//
#include <hip/hip_runtime.h>
#include <hip/hip_bf16.h>
#include <math.h>

#define NNODES 8192
#define NEDGES 131072
#define HID    512
#define UU     16
#define MM     512
#define NQKVS  2048   // packed q|k|v|s columns (Y layout; k,v quarters unused now)
#define KVREC  1536   // per-node KV record: 512B k(fp8) + 1024B v(bf16)

#if __has_builtin(__builtin_amdgcn_cvt_pk_f32_fp8) && __has_builtin(__builtin_amdgcn_cvt_pk_fp8_f32)
#define HAVE_FP8 1
#else
#define HAVE_FP8 0
#endif

#define KSCALE 16.0f
#define KISCALE (0.125f / 16.0f)   // score = (q . 16k) * 0.125/16

typedef __attribute__((ext_vector_type(8))) short bf16x8;
typedef __attribute__((ext_vector_type(4))) float f32x4;
typedef __attribute__((ext_vector_type(2))) float f32x2;

__device__ __forceinline__ float bf2f(ushort u) {
    return __uint_as_float(((unsigned)u) << 16);
}
__device__ __forceinline__ ushort f2bf(float f) {
    unsigned x = __float_as_uint(f);
    return (ushort)((x + 0x7fffu + ((x >> 16) & 1u)) >> 16);
}

// ---------------- weight transpose+convert + bias pack + cnt zeroing (fused) ----------------
__global__ __launch_bounds__(256) void k_wtb(
    const float* __restrict__ Wq, const float* __restrict__ Wk,
    const float* __restrict__ Wv, const float* __restrict__ Ws,
    const float* __restrict__ bq, const float* __restrict__ bk,
    const float* __restrict__ bv, const float* __restrict__ bs,
    ushort* __restrict__ Wt, float* __restrict__ bcat, int* __restrict__ zbuf)
{
    __shared__ float tile[64][65];
    int z = blockIdx.z;
    int t = threadIdx.x;
    if (z == 12) {
        int id = blockIdx.y * 8 + blockIdx.x;   // 0..63
        if (id < 24) {                          // bias pack [3][2048]
            int i = id * 256 + t;
            int l = i >> 11, j = i & 2047;
            int which = j >> 9, jj = j & 511;
            const float* b = which == 0 ? bq : which == 1 ? bk : which == 2 ? bv : bs;
            bcat[i] = b[l * HID + jj];
        } else if (id < 56) {                   // zero cnt+cursor (2*NNODES ints)
            int idx = (id - 24) * 512 + t * 2;
            zbuf[idx] = 0; zbuf[idx + 1] = 0;
        }
        return;
    }
    int l = z >> 2, which = z & 3;
    const float* src = (which == 0 ? Wq : which == 1 ? Wk : which == 2 ? Wv : Ws)
                       + (size_t)l * HID * HID;
    int k0 = blockIdx.x * 64, c0 = blockIdx.y * 64;
#pragma unroll
    for (int i = 0; i < 16; ++i) {
        int idx = i * 256 + t;
        int r = idx >> 6, c = idx & 63;
        tile[r][c] = src[(size_t)(k0 + r) * HID + c0 + c];
    }
    __syncthreads();
    ushort* dst = Wt + ((size_t)l * NQKVS + which * HID + c0) * HID + k0;
#pragma unroll
    for (int i = 0; i < 16; ++i) {
        int idx = i * 256 + t;
        int r = idx >> 6, c = idx & 63;
        dst[(size_t)r * HID + c] = f2bf(tile[c][r]);
    }
}

// ---------------- layer-0 linear (in=6) with fused feature build ----------------
__global__ __launch_bounds__(256) void k_lin0(
    const float* __restrict__ mc, const float* __restrict__ speeds,
    const float* __restrict__ dist, const float* __restrict__ ttg,
    const int* __restrict__ mask,
    const float* __restrict__ Wq0, const float* __restrict__ bq0,
    const float* __restrict__ Wk0, const float* __restrict__ bk0,
    const float* __restrict__ Wv0, const float* __restrict__ bv0,
    const float* __restrict__ Ws0, const float* __restrict__ bs0,
    ushort* __restrict__ Y, unsigned char* __restrict__ KV)
{
    int n = blockIdx.x;                // node
    int u = n >> 9, m = n & 511;
    float x[6];
    x[0] = mc[m * 2 + 0];
    x[1] = mc[m * 2 + 1];
    x[2] = (float)mask[u * MM + m];
    x[3] = speeds[u];
    x[4] = dist[u * MM + m];
    x[5] = ttg[u * MM + m];

    int j = threadIdx.x;               // 0..255 -> cols j*8..j*8+7
    int col0 = j * 8;
    int which = col0 >> 9, jj = col0 & 511;
    const float* W = which == 0 ? Wq0 : which == 1 ? Wk0 : which == 2 ? Wv0 : Ws0;
    const float* b = which == 0 ? bq0 : which == 1 ? bk0 : which == 2 ? bv0 : bs0;
    float s[8];
#pragma unroll
    for (int uu = 0; uu < 8; ++uu) s[uu] = b[jj + uu];
#pragma unroll
    for (int t = 0; t < 6; ++t)
#pragma unroll
        for (int uu = 0; uu < 8; ++uu)
            s[uu] = fmaf(x[t], W[t * HID + jj + uu], s[uu]);
    if (which == 0 || which == 3) {            // q, skip -> Y
        bf16x8 o8;
#pragma unroll
        for (int uu = 0; uu < 8; ++uu) o8[uu] = (short)f2bf(s[uu]);
        *(bf16x8*)(Y + (size_t)n * NQKVS + col0) = o8;
    } else if (which == 2) {                   // v -> KV (bf16)
        bf16x8 o8;
#pragma unroll
        for (int uu = 0; uu < 8; ++uu) o8[uu] = (short)f2bf(s[uu]);
        *(bf16x8*)(KV + (size_t)n * KVREC + 512 + jj * 2) = o8;
    } else {                                   // k -> KV (fp8, scaled)
#if HAVE_FP8
        int w0 = __builtin_amdgcn_cvt_pk_fp8_f32(s[0] * KSCALE, s[1] * KSCALE, 0, false);
        w0     = __builtin_amdgcn_cvt_pk_fp8_f32(s[2] * KSCALE, s[3] * KSCALE, w0, true);
        int w1 = __builtin_amdgcn_cvt_pk_fp8_f32(s[4] * KSCALE, s[5] * KSCALE, 0, false);
        w1     = __builtin_amdgcn_cvt_pk_fp8_f32(s[6] * KSCALE, s[7] * KSCALE, w1, true);
        uint2 uu2; uu2.x = (unsigned)w0; uu2.y = (unsigned)w1;
        *(uint2*)(KV + (size_t)n * KVREC + jj) = uu2;
#else
        bf16x8 o8;
#pragma unroll
        for (int uu = 0; uu < 8; ++uu) o8[uu] = (short)f2bf(s[uu]);
        *(bf16x8*)(KV + (size_t)n * KVREC + jj * 2) = o8;   // bf16 fallback k (KVREC unused v slot shifts)
#endif
    }
}

// ---------------- bf16 MFMA GEMM: [8192][512] @ Wt^T + bias -> Y(q,s) / KV(k,v) ----------------
// 128x128 tile, BK=64, 4 waves (2x2), 64KB LDS double-buffered -> 2 blocks/CU.
// (round-4/5 proven structure: stage 8-row x 128B slabs, XOR swizzle both-sides)
#define GBM 128
#define GBN 128
#define GBK 64
#define TILEB (GBM * GBK * 2)   // 16384 B per matrix tile
#define BUFB  (2 * TILEB)       // 32768 B per buffer (A+B)

__device__ __forceinline__ void stage_tile(
    const ushort* __restrict__ Ag, const ushort* __restrict__ Bg,
    char* __restrict__ base, int t)
{
    const int lane = t & 63;
    const int w = t >> 6;           // wave 0..3
    const int r8 = lane >> 3;       // row within 8-row slab
    const int c  = lane & 7;        // col16 slot
    const int csw = c ^ r8;         // XOR-swizzled source col
#pragma unroll
    for (int i = 0; i < 4; ++i) {
        int r0 = (w * 4 + i) * 8;   // 0,8,...,120
        __builtin_amdgcn_global_load_lds(
            (const __attribute__((address_space(1))) void*)(Ag + (size_t)(r0 + r8) * HID + csw * 8),
            (__attribute__((address_space(3))) void*)(base + r0 * 128 + lane * 16), 16, 0, 0);
        __builtin_amdgcn_global_load_lds(
            (const __attribute__((address_space(1))) void*)(Bg + (size_t)(r0 + r8) * HID + csw * 8),
            (__attribute__((address_space(3))) void*)(base + TILEB + r0 * 128 + lane * 16), 16, 0, 0);
    }
}

__global__ __launch_bounds__(256, 2) void k_gemm(
    const ushort* __restrict__ A,    // [8192][512] bf16
    const ushort* __restrict__ Bt,   // [2048][512] bf16 (weights, [n][k])
    const float* __restrict__ bias,  // [2048] fp32
    ushort* __restrict__ Y,          // [8192][2048] bf16 (q,s quarters only)
    unsigned char* __restrict__ KV)  // [8192][1536] packed k(fp8)+v(bf16)
{
    __shared__ char lds[2 * BUFB];   // 65536 B
    const int t = threadIdx.x;
    // bijective XCD remap (1024 blocks, 8 XCDs, m-band per XCD)
    const int bid = blockIdx.x;
    const int xcd = bid & 7;
    const int ii  = bid >> 3;                 // 0..127
    const int mi  = (xcd << 3) | (ii & 7);    // 0..63
    const int ni  = ii >> 3;                  // 0..15
    const int m0 = mi * GBM, n0 = ni * GBN;

    const int wid = t >> 6, lane = t & 63;
    const int wr = wid >> 1, wc = wid & 1;    // 2x2 waves, 64x64 out each
    const int l15 = lane & 15, lkq = lane >> 4;

    f32x4 acc[4][4] = {};

    const ushort* Ab = A + (size_t)m0 * HID;
    const ushort* Bb = Bt + (size_t)n0 * HID;

    stage_tile(Ab, Bb, lds, t);
    int cur = 0;
    const int NKS = HID / GBK;   // 8
    for (int T = 0; T < NKS; ++T) {
        __syncthreads();         // drains stage of buf[cur]; protects buf[cur^1] rewrite
        if (T + 1 < NKS)
            stage_tile(Ab + (T + 1) * GBK, Bb + (T + 1) * GBK,
                       lds + (cur ^ 1) * BUFB, t);
        const char* la = lds + cur * BUFB;
        const char* lb = la + TILEB;
#pragma unroll
        for (int kh = 0; kh < 2; ++kh) {
            const int kq = kh * 4 + lkq;
            const int sw = (kq ^ (l15 & 7)) << 4;
            bf16x8 a[4], b[4];
#pragma unroll
            for (int i = 0; i < 4; ++i)
                a[i] = *(const bf16x8*)(la + (wr * 64 + i * 16 + l15) * 128 + sw);
#pragma unroll
            for (int j = 0; j < 4; ++j)
                b[j] = *(const bf16x8*)(lb + (wc * 64 + j * 16 + l15) * 128 + sw);
#pragma unroll
            for (int i = 0; i < 4; ++i)
#pragma unroll
                for (int j = 0; j < 4; ++j)
                    acc[i][j] = __builtin_amdgcn_mfma_f32_16x16x32_bf16(a[i], b[j], acc[i][j], 0, 0, 0);
        }
        cur ^= 1;
    }

    const int whichq = n0 >> 9;   // 0=q 1=k 2=v 3=s (128-tile never straddles quarters)
    // epilogue: C/D layout col=lane&15, row=(lane>>4)*4+reg
#pragma unroll
    for (int i = 0; i < 4; ++i) {
        int row = m0 + wr * 64 + i * 16 + lkq * 4;
#pragma unroll
        for (int j = 0; j < 4; ++j) {
            int col = n0 + wc * 64 + j * 16 + l15;
            float bc = bias[col];
            f32x4 r = acc[i][j];
#pragma unroll
            for (int g = 0; g < 4; ++g) {
                float val = r[g] + bc;
                if (whichq == 0 || whichq == 3) {
                    Y[(size_t)(row + g) * NQKVS + col] = f2bf(val);
                } else if (whichq == 2) {          // v -> KV bf16
                    *(ushort*)(KV + (size_t)(row + g) * KVREC + 512 + (col - 1024) * 2) = f2bf(val);
                } else {                            // k -> KV fp8
#if HAVE_FP8
                    int pk = __builtin_amdgcn_cvt_pk_fp8_f32(val * KSCALE, val * KSCALE, 0, false);
                    KV[(size_t)(row + g) * KVREC + (col - 512)] = (unsigned char)(pk & 0xff);
#else
                    *(ushort*)(KV + (size_t)(row + g) * KVREC + (col - 512) * 2) = f2bf(val);
#endif
                }
            }
        }
    }
}

// ---------------- CSR build ----------------
__global__ __launch_bounds__(256) void k_hist(const int* __restrict__ dst, int* __restrict__ cnt)
{
    int e = blockIdx.x * blockDim.x + threadIdx.x;
    if (e < NEDGES) atomicAdd(&cnt[dst[e]], 1);
}

// parallel scan: 1024 threads, 8 elems each, wave-scan + cross-wave offsets
__global__ __launch_bounds__(1024) void k_scan(const int* __restrict__ cnt, int* __restrict__ indptr)
{
    __shared__ int wsum[16];
    __shared__ int woff[16];
    int t = threadIdx.x;
    int base = t * 8;
    int v[8];
    int s = 0;
#pragma unroll
    for (int i = 0; i < 8; ++i) { v[i] = cnt[base + i]; s += v[i]; }
    int lane = t & 63, w = t >> 6;
    int incl = s;
#pragma unroll
    for (int off = 1; off < 64; off <<= 1) {
        int u = __shfl_up(incl, off);
        if (lane >= off) incl += u;
    }
    if (lane == 63) wsum[w] = incl;
    __syncthreads();
    if (t == 0) {
        int run = 0;
#pragma unroll
        for (int i = 0; i < 16; ++i) { woff[i] = run; run += wsum[i]; }
    }
    __syncthreads();
    int run = woff[w] + incl - s;     // exclusive prefix for this chunk
#pragma unroll
    for (int i = 0; i < 8; ++i) { indptr[base + i] = run; run += v[i]; }
    if (t == 1023) indptr[NNODES] = run;
}

__global__ __launch_bounds__(256) void k_scatter(
    const int* __restrict__ src, const int* __restrict__ dst,
    const int* __restrict__ indptr, int* __restrict__ cursor, int* __restrict__ ssrc)
{
    int e = blockIdx.x * blockDim.x + threadIdx.x;
    if (e >= NEDGES) return;
    int d = dst[e];
    int p = atomicAdd(&cursor[d], 1);
    ssrc[indptr[d] + p] = src[e];
}

// ---------------- per-node attention (1 wave/node, 4 nodes/block), 2-deep prefetch ----------------
// lane l handles channels [l*8, l*8+8); heads are 8-lane groups (shfl_xor 1,2,4).
// k (fp8) and v (bf16) from the packed per-node KV record (one 1.5KB contiguous run).
__global__ __launch_bounds__(256) void k_attn(
    const int* __restrict__ indptr, const int* __restrict__ ssrc,
    const ushort* __restrict__ Y,   // [N][2048] (q, s quarters)
    const unsigned char* __restrict__ KV,   // [N][1536]
    ushort* __restrict__ X)         // [N][512] bf16 out
{
    int n = blockIdx.x * 4 + (threadIdx.x >> 6);
    if (n >= NNODES) return;
    int l = threadIdx.x & 63;
    int cbase = l * 8;
    const ushort* yq = Y + (size_t)n * NQKVS + cbase;
    float qf[8];
    {
        bf16x8 q8 = *(const bf16x8*)yq;
#pragma unroll
        for (int j = 0; j < 8; ++j) qf[j] = bf2f((ushort)q8[j]);
    }
    float mrun = -INFINITY, ssum = 0.f;
    float acc[8] = {};
    int e0 = indptr[n], e1 = indptr[n + 1];
#if HAVE_FP8
    uint2 ka = {}, kb = {};
#define KLOAD(K_, base_) K_ = *(const uint2*)((base_) + cbase)
#else
    bf16x8 ka = {}, kb = {};
#define KLOAD(K_, base_) K_ = *(const bf16x8*)((base_) + cbase * 2)
#endif
    bf16x8 va = {}, vb = {};
    if (e0 < e1) {
        const unsigned char* r = KV + (size_t)ssrc[e0] * KVREC;
        KLOAD(ka, r);
        va = *(const bf16x8*)(r + 512 + cbase * 2);
    }
    if (e0 + 1 < e1) {
        const unsigned char* r = KV + (size_t)ssrc[e0 + 1] * KVREC;
        KLOAD(kb, r);
        vb = *(const bf16x8*)(r + 512 + cbase * 2);
    }
    for (int e = e0; e < e1; ++e) {
        auto k8 = ka; bf16x8 v8 = va;
        ka = kb; va = vb;
        int en = e + 2;
        if (en < e1) {
            const unsigned char* r = KV + (size_t)ssrc[en] * KVREC;
            KLOAD(kb, r);
            vb = *(const bf16x8*)(r + 512 + cbase * 2);
        }
        float part = 0.f;
#if HAVE_FP8
        {
            f32x2 k01 = __builtin_amdgcn_cvt_pk_f32_fp8((int)k8.x, false);
            f32x2 k23 = __builtin_amdgcn_cvt_pk_f32_fp8((int)k8.x, true);
            f32x2 k45 = __builtin_amdgcn_cvt_pk_f32_fp8((int)k8.y, false);
            f32x2 k67 = __builtin_amdgcn_cvt_pk_f32_fp8((int)k8.y, true);
            part = fmaf(qf[0], k01.x, part); part = fmaf(qf[1], k01.y, part);
            part = fmaf(qf[2], k23.x, part); part = fmaf(qf[3], k23.y, part);
            part = fmaf(qf[4], k45.x, part); part = fmaf(qf[5], k45.y, part);
            part = fmaf(qf[6], k67.x, part); part = fmaf(qf[7], k67.y, part);
        }
        const float smul = KISCALE;
#else
#pragma unroll
        for (int j = 0; j < 8; ++j) part = fmaf(qf[j], bf2f((ushort)k8[j]), part);
        const float smul = 0.125f;
#endif
        part += __shfl_xor(part, 1);
        part += __shfl_xor(part, 2);
        part += __shfl_xor(part, 4);
        float score = part * smul;
        float mnew = fmaxf(mrun, score);
        float sc = __expf(mrun - mnew);
        float p = __expf(score - mnew);
        ssum = ssum * sc + p;
#pragma unroll
        for (int j = 0; j < 8; ++j)
            acc[j] = fmaf(acc[j], sc, p * bf2f((ushort)v8[j]));
        mrun = mnew;
    }
    float inv = ssum > 0.f ? 1.f / ssum : 0.f;
    bf16x8 o8;
#pragma unroll
    for (int j = 0; j < 8; ++j) {
        float o = fmaxf(fmaf(acc[j], inv, bf2f(yq[1536 + j])), 0.f);  // + skip, ReLU
        o8[j] = (short)f2bf(o);
    }
    *(bf16x8*)(X + (size_t)n * HID + cbase) = o8;
}

// ---------------- pooling: xsumP[u][p][c] = partial sums over 64 rows ----------------
__global__ __launch_bounds__(512) void k_pool(const ushort* __restrict__ X, float* __restrict__ xsumP)
{
    int u = blockIdx.x;
    int pp = blockIdx.y;               // 0..7
    int c = threadIdx.x;
    const ushort* base = X + ((size_t)u * MM + pp * 64) * HID + c;
    float s = 0.f;
    for (int m = 0; m < 64; ++m) s += bf2f(base[(size_t)m * HID]);
    xsumP[((size_t)u * 8 + pp) * HID + c] = s;
}

// ---------------- fused: emb = xsum @ Wout + M*bout, then actor/critic head ----------------
__global__ __launch_bounds__(512) void k_embhead(
    const float* __restrict__ xsumP, const float* __restrict__ Wout,
    const float* __restrict__ bout,
    const float* __restrict__ uavs, const float* __restrict__ speeds,
    const float* __restrict__ Wc1, const float* __restrict__ bc1,
    const float* __restrict__ Wc2, const float* __restrict__ bc2,
    float* __restrict__ out)
{
    __shared__ float xs[HID];
    __shared__ float comb[67];
    __shared__ float red[128];
    int u = blockIdx.x, c = threadIdx.x;
    float s = 0.f;
#pragma unroll
    for (int p = 0; p < 8; ++p) s += xsumP[((size_t)u * 8 + p) * HID + c];
    xs[c] = s;
    __syncthreads();
    if (c < 64) {
        float a = 0.f;
        for (int i = 0; i < HID; ++i) a = fmaf(xs[i], Wout[i * 64 + c], a);
        comb[2 + c] = a + 512.0f * bout[c];
    }
    if (c == 64) { comb[0] = uavs[u * 2]; comb[1] = uavs[u * 2 + 1]; }
    if (c == 65) comb[66] = speeds[u];
    __syncthreads();
    if (c < 128) {
        float a = bc1[c];
        for (int i = 0; i < 67; ++i) a = fmaf(comb[i], Wc1[i * 128 + c], a);
        a = fmaxf(a, 0.f);
        red[c] = a * Wc2[c];
    }
    __syncthreads();
    for (int sft = 64; sft > 0; sft >>= 1) {
        if (c < sft) red[c] += red[c + sft];
        __syncthreads();
    }
    if (c == 0) {
        out[u]      = 1.0f;                 // softmax over singleton axis
        out[16 + u] = red[0] + bc2[0];
    }
}

extern "C" void kernel_launch(void* const* d_in, const int* in_sizes, int n_in,
                              void* d_out, int out_size, void* d_ws, size_t ws_size,
                              hipStream_t stream)
{
    const float* mission_coords = (const float*)d_in[0];
    const float* uavs_info      = (const float*)d_in[1];
    const float* speeds         = (const float*)d_in[2];
    const float* dist_matrix    = (const float*)d_in[3];
    const float* timetogo       = (const float*)d_in[4];
    const int*   action_mask    = (const int*)d_in[5];
    const int*   edge_index     = (const int*)d_in[6];
    const float* Wq0 = (const float*)d_in[8];  const float* bq0 = (const float*)d_in[9];
    const float* Wk0 = (const float*)d_in[10]; const float* bk0 = (const float*)d_in[11];
    const float* Wv0 = (const float*)d_in[12]; const float* bv0 = (const float*)d_in[13];
    const float* Ws0 = (const float*)d_in[14]; const float* bs0 = (const float*)d_in[15];
    const float* Wq  = (const float*)d_in[16]; const float* bq  = (const float*)d_in[17];
    const float* Wk  = (const float*)d_in[18]; const float* bk  = (const float*)d_in[19];
    const float* Wv  = (const float*)d_in[20]; const float* bv  = (const float*)d_in[21];
    const float* Ws  = (const float*)d_in[22]; const float* bs  = (const float*)d_in[23];
    const float* Wout = (const float*)d_in[24]; const float* bout = (const float*)d_in[25];
    const float* Wc1 = (const float*)d_in[30]; const float* bc1 = (const float*)d_in[31];
    const float* Wc2 = (const float*)d_in[32]; const float* bc2 = (const float*)d_in[33];
    float* out = (float*)d_out;

    const int* e_src = edge_index;
    const int* e_dst = edge_index + NEDGES;

    // ---- workspace carve ----
    char* p = (char*)d_ws;
    ushort* Ybf = (ushort*)p;  p += (size_t)NNODES * NQKVS * 2;   // 32 MB
    ushort* Xbf = (ushort*)p;  p += (size_t)NNODES * HID * 2;     // 8 MB
    ushort* Wt  = (ushort*)p;  p += (size_t)3 * NQKVS * HID * 2;  // 6 MB
    unsigned char* KV = (unsigned char*)p; p += (size_t)NNODES * KVREC; // 12 MB
    float* bcat = (float*)p;   p += (size_t)3 * NQKVS * 4;
    float* xsumP = (float*)p;  p += (size_t)UU * 8 * HID * 4;
    int* cnt    = (int*)p;     p += (size_t)NNODES * 4;           // cnt+cursor adjacent
    int* cursor = (int*)p;     p += (size_t)NNODES * 4;
    int* indptr = (int*)p;     p += (size_t)(NNODES + 1) * 4;
    int* ssrc   = (int*)p;     p += (size_t)NEDGES * 4;

    // ---- prep: weights+bias+zeroing (fused), CSR ----
    k_wtb<<<dim3(8, 8, 13), 256, 0, stream>>>(Wq, Wk, Wv, Ws, bq, bk, bv, bs,
                                              Wt, bcat, cnt);
    k_hist<<<NEDGES / 256, 256, 0, stream>>>(e_dst, cnt);
    k_scan<<<1, 1024, 0, stream>>>(cnt, indptr);
    k_scatter<<<NEDGES / 256, 256, 0, stream>>>(e_src, e_dst, indptr, cursor, ssrc);

    // ---- layer 0 (in=6, fused feature build) ----
    k_lin0<<<NNODES, 256, 0, stream>>>(mission_coords, speeds, dist_matrix, timetogo,
                                       action_mask, Wq0, bq0, Wk0, bk0, Wv0, bv0,
                                       Ws0, bs0, Ybf, KV);
    k_attn<<<NNODES / 4, 256, 0, stream>>>(indptr, ssrc, Ybf, KV, Xbf);

    // ---- layers 1..3: fused q|k|v|s MFMA GEMM + attention ----
    const int ngblocks = (NNODES / GBM) * (NQKVS / GBN);   // 1024
    for (int l = 0; l < 3; ++l) {
        k_gemm<<<ngblocks, 256, 0, stream>>>(Xbf, Wt + (size_t)l * NQKVS * HID,
                                             bcat + l * NQKVS, Ybf, KV);
        k_attn<<<NNODES / 4, 256, 0, stream>>>(indptr, ssrc, Ybf, KV, Xbf);
    }

    // ---- pooling + fused embedding/head ----
    k_pool<<<dim3(UU, 8), 512, 0, stream>>>(Xbf, xsumP);
    k_embhead<<<UU, 512, 0, stream>>>(xsumP, Wout, bout, uavs_info, speeds,
                                      Wc1, bc1, Wc2, bc2, out);
}